// Round 8
// baseline (293.269 us; speedup 1.0000x reference)
//
#include <hip/hip_runtime.h>
#include <math.h>

// Problem constants (fixed by reference setup_inputs)
constexpr int Bn = 4096, Sn = 256, Tn = 64;
constexpr int Dn = 18, Hn = 16, Ln = 3;
constexpr float EPS = 1e-5f;
constexpr int R = 4;                       // rows per thread (k1/k3 register blocking)

// d_out layout: x_recon (B,S,D) | x_pred (B,T,D) | prob (B,1) | z_seq (B,S,L)
constexpr size_t OFF_XP   = (size_t)Bn * Sn * Dn;            // 18874368
constexpr size_t OFF_PROB = OFF_XP + (size_t)Bn * Tn * Dn;   // 23592960
constexpr size_t OFF_ZS   = OFF_PROB + (size_t)Bn;           // 23597056

__device__ __forceinline__ float fast_tanh(float x) {
    float ax = fabsf(x);
    float e  = __expf(-2.0f * ax);
    float r  = (1.0f - e) / (1.0f + e);
    return copysignf(r, x);
}

// K1: fused encode -> z_seq -> decode -> x_recon + z_mean/classifier.
// Block = 256 threads covers 4 batch elements (1024 rows); thread s handles
// seq position s of batches 4*blockIdx+{0..3}. Weight-outer/row-inner loops:
// every uniform weight s_load feeds 4 FMAs (rounds 2/5/6 showed the ~700-dword
// per-row weight restream was the latency bottleneck: VALUBusy<=30%, BW<=31%).
// No LDS / no barriers in the hot path; per-h[r][j] accumulation order is
// k-ascending, identical to the previously-passing version.
__global__ __launch_bounds__(256) void k1_encdec(
    const float* __restrict__ x,
    const float* __restrict__ ew1, const float* __restrict__ eb1,
    const float* __restrict__ eg,  const float* __restrict__ ebb,
    const float* __restrict__ em,  const float* __restrict__ ev,
    const float* __restrict__ ew2, const float* __restrict__ eb2,
    const float* __restrict__ dw1, const float* __restrict__ db1,
    const float* __restrict__ dg,  const float* __restrict__ dbn,
    const float* __restrict__ dm,  const float* __restrict__ dv,
    const float* __restrict__ dw2, const float* __restrict__ db2,
    const float* __restrict__ cw1, const float* __restrict__ cb1,
    const float* __restrict__ cw2, const float* __restrict__ cb2,
    float* __restrict__ xrec, float* __restrict__ prob, float* __restrict__ zseq)
{
    const int s = threadIdx.x;
    const size_t row0 = (size_t)blockIdx.x * (R * Sn) + s;   // row r = row0 + r*Sn

    // ---- encode layer 1 (k-streamed x, h[r][j] accumulates k ascending) ----
    float h[R][Hn];
    #pragma unroll
    for (int j = 0; j < Hn; ++j) {
        float b = eb1[j];
        #pragma unroll
        for (int r = 0; r < R; ++r) h[r][j] = b;
    }
    #pragma unroll
    for (int kk = 0; kk < Dn / 2; ++kk) {
        float2 xa[R];
        #pragma unroll
        for (int r = 0; r < R; ++r)
            xa[r] = *reinterpret_cast<const float2*>(x + (row0 + (size_t)r * Sn) * Dn + 2 * kk);
        #pragma unroll
        for (int j = 0; j < Hn; ++j) {
            float w0 = ew1[j * Dn + 2 * kk];
            float w1 = ew1[j * Dn + 2 * kk + 1];
            #pragma unroll
            for (int r = 0; r < R; ++r) {
                h[r][j] = fmaf(w0, xa[r].x, h[r][j]);
                h[r][j] = fmaf(w1, xa[r].y, h[r][j]);
            }
        }
    }
    // relu + folded BN
    #pragma unroll
    for (int j = 0; j < Hn; ++j) {
        float sc = eg[j] / sqrtf(ev[j] + EPS);
        float sh = ebb[j] - em[j] * sc;
        #pragma unroll
        for (int r = 0; r < R; ++r)
            h[r][j] = fmaf(fmaxf(h[r][j], 0.0f), sc, sh);
    }

    // ---- encode layer 2 -> z (per (r,c): j ascending) ----
    float zz[R][Ln];
    #pragma unroll
    for (int c = 0; c < Ln; ++c) {
        float b = eb2[c];
        #pragma unroll
        for (int r = 0; r < R; ++r) zz[r][c] = b;
    }
    #pragma unroll
    for (int j = 0; j < Hn; ++j) {
        #pragma unroll
        for (int c = 0; c < Ln; ++c) {
            float w = ew2[c * Hn + j];
            #pragma unroll
            for (int r = 0; r < R; ++r) zz[r][c] = fmaf(w, h[r][j], zz[r][c]);
        }
    }
    // z_seq stores (12 B per row, lane-contiguous)
    #pragma unroll
    for (int r = 0; r < R; ++r) {
        float* zp = zseq + (row0 + (size_t)r * Sn) * Ln;
        zp[0] = zz[r][0]; zp[1] = zz[r][1]; zp[2] = zz[r][2];
    }

    // ---- decode layer 1 + BN ----
    float h2[R][Hn];
    #pragma unroll
    for (int j = 0; j < Hn; ++j) {
        float w0 = dw1[j * Ln + 0], w1 = dw1[j * Ln + 1], w2 = dw1[j * Ln + 2];
        float b  = db1[j];
        float sc = dg[j] / sqrtf(dv[j] + EPS);
        float sh = dbn[j] - dm[j] * sc;
        #pragma unroll
        for (int r = 0; r < R; ++r) {
            float a = fmaf(w0, zz[r][0], b);
            a = fmaf(w1, zz[r][1], a);
            a = fmaf(w2, zz[r][2], a);
            h2[r][j] = fmaf(fmaxf(a, 0.0f), sc, sh);
        }
    }
    // ---- decode output, streamed float2 stores (per (r,m): j ascending) ----
    #pragma unroll
    for (int m = 0; m < Dn; m += 2) {
        float o0[R], o1[R];
        #pragma unroll
        for (int r = 0; r < R; ++r) { o0[r] = db2[m]; o1[r] = db2[m + 1]; }
        #pragma unroll
        for (int j = 0; j < Hn; ++j) {
            float wa = dw2[m * Hn + j];
            float wb = dw2[(m + 1) * Hn + j];
            #pragma unroll
            for (int r = 0; r < R; ++r) {
                o0[r] = fmaf(wa, h2[r][j], o0[r]);
                o1[r] = fmaf(wb, h2[r][j], o1[r]);
            }
        }
        #pragma unroll
        for (int r = 0; r < R; ++r)
            *reinterpret_cast<float2*>(xrec + (row0 + (size_t)r * Sn) * Dn + m) =
                make_float2(o0[r], o1[r]);
    }

    // ---- z_mean over S (12 values: 4 batches x 3 comps) + classifier ----
    float acc[R][Ln];
    #pragma unroll
    for (int r = 0; r < R; ++r)
        #pragma unroll
        for (int c = 0; c < Ln; ++c) acc[r][c] = zz[r][c];
    #pragma unroll
    for (int off = 32; off > 0; off >>= 1) {
        #pragma unroll
        for (int r = 0; r < R; ++r)
            #pragma unroll
            for (int c = 0; c < Ln; ++c)
                acc[r][c] += __shfl_down(acc[r][c], off);
    }
    __shared__ float red[4][R][Ln];
    const int lane = s & 63, wid = s >> 6;
    if (lane == 0) {
        #pragma unroll
        for (int r = 0; r < R; ++r)
            #pragma unroll
            for (int c = 0; c < Ln; ++c) red[wid][r][c] = acc[r][c];
    }
    __syncthreads();
    if (s < R) {  // thread s handles batch 4*blockIdx + s
        float m0 = (red[0][s][0] + red[1][s][0] + red[2][s][0] + red[3][s][0]) * (1.0f / Sn);
        float m1 = (red[0][s][1] + red[1][s][1] + red[2][s][1] + red[3][s][1]) * (1.0f / Sn);
        float m2 = (red[0][s][2] + red[1][s][2] + red[2][s][2] + red[3][s][2]) * (1.0f / Sn);
        float logit = cb2[0];
        #pragma unroll
        for (int j = 0; j < 4; ++j) {
            float a = fmaf(cw1[j * 3 + 0], m0, cb1[j]);
            a = fmaf(cw1[j * 3 + 1], m1, a);
            a = fmaf(cw1[j * 3 + 2], m2, a);
            a = fmaxf(a, 0.0f);
            logit = fmaf(cw2[j], a, logit);
        }
        prob[blockIdx.x * R + s] = 1.0f / (1.0f + __expf(-logit));
    }
}

// K2: sequential ODE scan, one thread per batch element; 64 blocks x 64
// threads spreads the 64 waves across more CUs (latency-bound serial chain).
// zlayout 0: scratch [t][B][3] in d_ws (lane-contiguous stores);
// zlayout 1: fallback, stash z in first 12 B of each x_pred row.
__global__ __launch_bounds__(64) void k2_ode(
    const float* __restrict__ zseq,
    const float* __restrict__ ow1, const float* __restrict__ ob1,
    const float* __restrict__ ow2, const float* __restrict__ ob2,
    float* __restrict__ zscr, int zlayout)
{
    const int b = blockIdx.x * blockDim.x + threadIdx.x;
    const float* zp = zseq + ((size_t)b * Sn + (Sn - 1)) * Ln;
    float z0 = zp[0], z1 = zp[1], z2 = zp[2];

    float w1[8][3], bb1[8], w2v[3][8], bb2[3];
    #pragma unroll
    for (int j = 0; j < 8; ++j) {
        bb1[j] = ob1[j];
        #pragma unroll
        for (int k = 0; k < 3; ++k) w1[j][k] = ow1[j * 3 + k];
    }
    #pragma unroll
    for (int i = 0; i < 3; ++i) {
        bb2[i] = ob2[i];
        #pragma unroll
        for (int j = 0; j < 8; ++j) w2v[i][j] = ow2[i * 8 + j];
    }

    for (int t = 0; t < Tn; ++t) {
        float a[8];
        #pragma unroll
        for (int j = 0; j < 8; ++j) {
            float u = fmaf(w1[j][0], z0, bb1[j]);
            u = fmaf(w1[j][1], z1, u);
            u = fmaf(w1[j][2], z2, u);
            a[j] = fast_tanh(u);
        }
        float d0 = bb2[0], d1 = bb2[1], d2 = bb2[2];
        #pragma unroll
        for (int j = 0; j < 8; ++j) {
            d0 = fmaf(w2v[0][j], a[j], d0);
            d1 = fmaf(w2v[1][j], a[j], d1);
            d2 = fmaf(w2v[2][j], a[j], d2);
        }
        z0 = fmaf(0.1f, d0, z0);
        z1 = fmaf(0.1f, d1, z1);
        z2 = fmaf(0.1f, d2, z2);
        size_t idx = (zlayout == 0) ? ((size_t)t * Bn + b) * Ln
                                    : ((size_t)b * Tn + t) * Dn;
        zscr[idx + 0] = z0; zscr[idx + 1] = z1; zscr[idx + 2] = z2;
    }
}

// K3: decode x_pred rows, R=4 rows per thread (same weight-amortized,
// barrier-free structure as K1's decode). 256 blocks x 256 threads.
__global__ __launch_bounds__(256) void k3_decpred(
    const float* __restrict__ dw1, const float* __restrict__ db1,
    const float* __restrict__ dg,  const float* __restrict__ dbn,
    const float* __restrict__ dm,  const float* __restrict__ dv,
    const float* __restrict__ dw2, const float* __restrict__ db2,
    const float* __restrict__ zscr, int zlayout,
    float* __restrict__ xpred)
{
    const int s = threadIdx.x;
    const size_t row0 = (size_t)blockIdx.x * (R * 256) + s;  // row r = row0 + r*256

    // z reads (all before any store; rows are thread-private)
    float zz[R][Ln];
    #pragma unroll
    for (int r = 0; r < R; ++r) {
        size_t row = row0 + (size_t)r * 256;
        size_t zidx = (zlayout == 0) ? (((row & 63) * Bn + (row >> 6)) * Ln)
                                     : row * Dn;
        zz[r][0] = zscr[zidx + 0];
        zz[r][1] = zscr[zidx + 1];
        zz[r][2] = zscr[zidx + 2];
    }

    float h2[R][Hn];
    #pragma unroll
    for (int j = 0; j < Hn; ++j) {
        float w0 = dw1[j * Ln + 0], w1 = dw1[j * Ln + 1], w2 = dw1[j * Ln + 2];
        float b  = db1[j];
        float sc = dg[j] / sqrtf(dv[j] + EPS);
        float sh = dbn[j] - dm[j] * sc;
        #pragma unroll
        for (int r = 0; r < R; ++r) {
            float a = fmaf(w0, zz[r][0], b);
            a = fmaf(w1, zz[r][1], a);
            a = fmaf(w2, zz[r][2], a);
            h2[r][j] = fmaf(fmaxf(a, 0.0f), sc, sh);
        }
    }
    #pragma unroll
    for (int m = 0; m < Dn; m += 2) {
        float o0[R], o1[R];
        #pragma unroll
        for (int r = 0; r < R; ++r) { o0[r] = db2[m]; o1[r] = db2[m + 1]; }
        #pragma unroll
        for (int j = 0; j < Hn; ++j) {
            float wa = dw2[m * Hn + j];
            float wb = dw2[(m + 1) * Hn + j];
            #pragma unroll
            for (int r = 0; r < R; ++r) {
                o0[r] = fmaf(wa, h2[r][j], o0[r]);
                o1[r] = fmaf(wb, h2[r][j], o1[r]);
            }
        }
        #pragma unroll
        for (int r = 0; r < R; ++r)
            *reinterpret_cast<float2*>(xpred + (row0 + (size_t)r * 256) * Dn + m) =
                make_float2(o0[r], o1[r]);
    }
}

extern "C" void kernel_launch(void* const* d_in, const int* in_sizes, int n_in,
                              void* d_out, int out_size, void* d_ws, size_t ws_size,
                              hipStream_t stream)
{
    const float* x   = (const float*)d_in[0];
    // d_in[1] = t_span: only its length (T=64) matters; unused at runtime.
    const float* ew1 = (const float*)d_in[2];
    const float* eb1 = (const float*)d_in[3];
    const float* eg  = (const float*)d_in[4];
    const float* ebb = (const float*)d_in[5];
    const float* em  = (const float*)d_in[6];
    const float* ev  = (const float*)d_in[7];
    const float* ew2 = (const float*)d_in[8];
    const float* eb2 = (const float*)d_in[9];
    const float* dw1 = (const float*)d_in[10];
    const float* db1 = (const float*)d_in[11];
    const float* dg  = (const float*)d_in[12];
    const float* dbn = (const float*)d_in[13];
    const float* dm  = (const float*)d_in[14];
    const float* dv  = (const float*)d_in[15];
    const float* dw2 = (const float*)d_in[16];
    const float* db2 = (const float*)d_in[17];
    const float* ow1 = (const float*)d_in[18];
    const float* ob1 = (const float*)d_in[19];
    const float* ow2 = (const float*)d_in[20];
    const float* ob2 = (const float*)d_in[21];
    const float* cw1 = (const float*)d_in[22];
    const float* cb1 = (const float*)d_in[23];
    const float* cw2 = (const float*)d_in[24];
    const float* cb2 = (const float*)d_in[25];

    float* out   = (float*)d_out;
    float* xrec  = out;
    float* xpred = out + OFF_XP;
    float* prob  = out + OFF_PROB;
    float* zseq  = out + OFF_ZS;

    // z-trajectory scratch: prefer d_ws ([t][B][3], coalesced K2 stores);
    // fall back to stashing inside x_pred rows if ws is too small.
    const size_t zbytes = (size_t)Bn * Tn * Ln * sizeof(float);
    float* zscr; int zlayout;
    if (ws_size >= zbytes) { zscr = (float*)d_ws; zlayout = 0; }
    else                   { zscr = xpred;        zlayout = 1; }

    k1_encdec<<<dim3(Bn / R), dim3(Sn), 0, stream>>>(
        x, ew1, eb1, eg, ebb, em, ev, ew2, eb2,
        dw1, db1, dg, dbn, dm, dv, dw2, db2,
        cw1, cb1, cw2, cb2, xrec, prob, zseq);

    k2_ode<<<dim3(Bn / 64), dim3(64), 0, stream>>>(
        zseq, ow1, ob1, ow2, ob2, zscr, zlayout);

    k3_decpred<<<dim3((Bn * Tn) / (R * 256)), dim3(256), 0, stream>>>(
        dw1, db1, dg, dbn, dm, dv, dw2, db2, zscr, zlayout, xpred);
}

// Round 11
// 273.019 us; speedup vs baseline: 1.0742x; 1.0742x over previous
//
#include <hip/hip_runtime.h>
#include <math.h>

// Problem constants (fixed by reference setup_inputs)
constexpr int Bn = 4096, Sn = 256, Tn = 64;
constexpr int Dn = 18, Hn = 16, Ln = 3;
constexpr float EPS = 1e-5f;
constexpr int R = 4;   // batches per block (K1) / row-groups per thread (K3)

// d_out layout: x_recon (B,S,D) | x_pred (B,T,D) | prob (B,1) | z_seq (B,S,L)
constexpr size_t OFF_XP   = (size_t)Bn * Sn * Dn;            // 18874368
constexpr size_t OFF_PROB = OFF_XP + (size_t)Bn * Tn * Dn;   // 23592960
constexpr size_t OFF_ZS   = OFF_PROB + (size_t)Bn;           // 23597056

__device__ __forceinline__ float fast_tanh(float x) {
    float ax = fabsf(x);
    float e  = __expf(-2.0f * ax);
    float r  = (1.0f - e) / (1.0f + e);
    return copysignf(r, x);
}

// K1: fused encode -> z_seq -> decode -> x_recon + z_mean/classifier.
// Evidence-driven structure (R5/R6/R8 counters):
//  - Global I/O via a 4-batch LDS tile (72 KB): batches 4b..4b+3 are one
//    contiguous 73728-B span -> dense float4 copies. (R8's direct strided
//    float2 stores caused 2x write amplification: WRITE 86->180 MB.)
//  - R=4 register blocking, weight-outer/row-inner: each uniform weight
//    s_load feeds 4 FMAs (R5's per-row weight restream left VALUBusy 28%
//    with both BW and VALU unsaturated).
//  - Weights stay in SGPRs via s_load broadcast, NOT in LDS (R6: per-FMA
//    LDS weight reads made the kernel LDS-pipe-bound, 97 us).
// Thread s handles seq position s of the block's 4 batches.
__global__ __launch_bounds__(256) void k1_encdec(
    const float* __restrict__ x,
    const float* __restrict__ ew1, const float* __restrict__ eb1,
    const float* __restrict__ eg,  const float* __restrict__ ebb,
    const float* __restrict__ em,  const float* __restrict__ ev,
    const float* __restrict__ ew2, const float* __restrict__ eb2,
    const float* __restrict__ dw1, const float* __restrict__ db1,
    const float* __restrict__ dg,  const float* __restrict__ dbn,
    const float* __restrict__ dm,  const float* __restrict__ dv,
    const float* __restrict__ dw2, const float* __restrict__ db2,
    const float* __restrict__ cw1, const float* __restrict__ cb1,
    const float* __restrict__ cw2, const float* __restrict__ cb2,
    float* __restrict__ xrec, float* __restrict__ prob, float* __restrict__ zseq)
{
    const int s = threadIdx.x;
    constexpr int TILE_F   = Sn * Dn;        // 4608 floats per batch tile
    constexpr int TILE4_F  = R * TILE_F;     // 18432 floats = 73728 B
    constexpr int TILE4_F4 = TILE4_F / 4;    // 4608 float4

    __shared__ float xt[TILE4_F];            // reused: x in, x_recon out
    __shared__ float red[4][R][Ln];

    // ---- dense coalesced load of the block's 4 contiguous batch tiles ----
    const size_t base = (size_t)blockIdx.x * TILE4_F;
    const float4* xg  = reinterpret_cast<const float4*>(x + base);
    float4*       xt4 = reinterpret_cast<float4*>(xt);
    #pragma unroll 4
    for (int i = s; i < TILE4_F4; i += 256) xt4[i] = xg[i];
    __syncthreads();

    // ---- encode layer 1 (x from LDS, h[r][j] accumulates k ascending) ----
    float h[R][Hn];
    #pragma unroll
    for (int j = 0; j < Hn; ++j) {
        float b = eb1[j];
        #pragma unroll
        for (int r = 0; r < R; ++r) h[r][j] = b;
    }
    #pragma unroll
    for (int kk = 0; kk < Dn / 2; ++kk) {
        float2 xa[R];
        #pragma unroll
        for (int r = 0; r < R; ++r)
            xa[r] = *reinterpret_cast<const float2*>(&xt[r * TILE_F + s * Dn + 2 * kk]);
        #pragma unroll
        for (int j = 0; j < Hn; ++j) {
            float w0 = ew1[j * Dn + 2 * kk];
            float w1 = ew1[j * Dn + 2 * kk + 1];
            #pragma unroll
            for (int r = 0; r < R; ++r) {
                h[r][j] = fmaf(w0, xa[r].x, h[r][j]);
                h[r][j] = fmaf(w1, xa[r].y, h[r][j]);
            }
        }
    }
    // relu + folded BN
    #pragma unroll
    for (int j = 0; j < Hn; ++j) {
        float sc = eg[j] / sqrtf(ev[j] + EPS);
        float sh = ebb[j] - em[j] * sc;
        #pragma unroll
        for (int r = 0; r < R; ++r)
            h[r][j] = fmaf(fmaxf(h[r][j], 0.0f), sc, sh);
    }

    // ---- encode layer 2 -> z ----
    float zz[R][Ln];
    #pragma unroll
    for (int c = 0; c < Ln; ++c) {
        float b = eb2[c];
        #pragma unroll
        for (int r = 0; r < R; ++r) zz[r][c] = b;
    }
    #pragma unroll
    for (int j = 0; j < Hn; ++j) {
        #pragma unroll
        for (int c = 0; c < Ln; ++c) {
            float w = ew2[c * Hn + j];
            #pragma unroll
            for (int r = 0; r < R; ++r) zz[r][c] = fmaf(w, h[r][j], zz[r][c]);
        }
    }
    // z_seq stores: rows are 12 B, lane-contiguous per r -> dense.
    #pragma unroll
    for (int r = 0; r < R; ++r) {
        float* zp = zseq + (((size_t)blockIdx.x * R + r) * Sn + s) * Ln;
        zp[0] = zz[r][0]; zp[1] = zz[r][1]; zp[2] = zz[r][2];
    }

    // ---- decode layer 1 + BN ----
    float h2[R][Hn];
    #pragma unroll
    for (int j = 0; j < Hn; ++j) {
        float w0 = dw1[j * Ln + 0], w1 = dw1[j * Ln + 1], w2 = dw1[j * Ln + 2];
        float b  = db1[j];
        float sc = dg[j] / sqrtf(dv[j] + EPS);
        float sh = dbn[j] - dm[j] * sc;
        #pragma unroll
        for (int r = 0; r < R; ++r) {
            float a = fmaf(w0, zz[r][0], b);
            a = fmaf(w1, zz[r][1], a);
            a = fmaf(w2, zz[r][2], a);
            h2[r][j] = fmaf(fmaxf(a, 0.0f), sc, sh);
        }
    }
    // ---- decode output into own LDS rows (no cross-thread overlap) ----
    #pragma unroll
    for (int m = 0; m < Dn; m += 2) {
        float o0[R], o1[R];
        #pragma unroll
        for (int r = 0; r < R; ++r) { o0[r] = db2[m]; o1[r] = db2[m + 1]; }
        #pragma unroll
        for (int j = 0; j < Hn; ++j) {
            float wa = dw2[m * Hn + j];
            float wb = dw2[(m + 1) * Hn + j];
            #pragma unroll
            for (int r = 0; r < R; ++r) {
                o0[r] = fmaf(wa, h2[r][j], o0[r]);
                o1[r] = fmaf(wb, h2[r][j], o1[r]);
            }
        }
        #pragma unroll
        for (int r = 0; r < R; ++r) {
            xt[r * TILE_F + s * Dn + m]     = o0[r];
            xt[r * TILE_F + s * Dn + m + 1] = o1[r];
        }
    }
    __syncthreads();

    // ---- dense coalesced store of x_recon ----
    float4* og = reinterpret_cast<float4*>(xrec + base);
    #pragma unroll 4
    for (int i = s; i < TILE4_F4; i += 256) og[i] = xt4[i];

    // ---- z_mean over S + classifier ----
    float acc[R][Ln];
    #pragma unroll
    for (int r = 0; r < R; ++r)
        #pragma unroll
        for (int c = 0; c < Ln; ++c) acc[r][c] = zz[r][c];
    #pragma unroll
    for (int off = 32; off > 0; off >>= 1) {
        #pragma unroll
        for (int r = 0; r < R; ++r)
            #pragma unroll
            for (int c = 0; c < Ln; ++c)
                acc[r][c] += __shfl_down(acc[r][c], off);
    }
    const int lane = s & 63, wid = s >> 6;
    if (lane == 0) {
        #pragma unroll
        for (int r = 0; r < R; ++r)
            #pragma unroll
            for (int c = 0; c < Ln; ++c) red[wid][r][c] = acc[r][c];
    }
    __syncthreads();
    if (s < R) {  // thread s handles batch R*blockIdx + s
        float m0 = (red[0][s][0] + red[1][s][0] + red[2][s][0] + red[3][s][0]) * (1.0f / Sn);
        float m1 = (red[0][s][1] + red[1][s][1] + red[2][s][1] + red[3][s][1]) * (1.0f / Sn);
        float m2 = (red[0][s][2] + red[1][s][2] + red[2][s][2] + red[3][s][2]) * (1.0f / Sn);
        float logit = cb2[0];
        #pragma unroll
        for (int j = 0; j < 4; ++j) {
            float a = fmaf(cw1[j * 3 + 0], m0, cb1[j]);
            a = fmaf(cw1[j * 3 + 1], m1, a);
            a = fmaf(cw1[j * 3 + 2], m2, a);
            a = fmaxf(a, 0.0f);
            logit = fmaf(cw2[j], a, logit);
        }
        prob[blockIdx.x * R + s] = 1.0f / (1.0f + __expf(-logit));
    }
}

// K2: sequential ODE scan, one thread per batch element; 64 blocks x 64
// threads (latency-bound serial chain, spread across CUs).
// z trajectory scratch layout: [b][t]*zstride (zstride=3 in d_ws; fallback
// zstride=18 stashes into x_pred rows). [b][t] order makes K3's reads DENSE;
// K2's scattered stores are only 3 MB from 64 slack-rich waves.
__global__ __launch_bounds__(64) void k2_ode(
    const float* __restrict__ zseq,
    const float* __restrict__ ow1, const float* __restrict__ ob1,
    const float* __restrict__ ow2, const float* __restrict__ ob2,
    float* __restrict__ zscr, int zstride)
{
    const int b = blockIdx.x * blockDim.x + threadIdx.x;
    const float* zp = zseq + ((size_t)b * Sn + (Sn - 1)) * Ln;
    float z0 = zp[0], z1 = zp[1], z2 = zp[2];

    float w1[8][3], bb1[8], w2v[3][8], bb2[3];
    #pragma unroll
    for (int j = 0; j < 8; ++j) {
        bb1[j] = ob1[j];
        #pragma unroll
        for (int k = 0; k < 3; ++k) w1[j][k] = ow1[j * 3 + k];
    }
    #pragma unroll
    for (int i = 0; i < 3; ++i) {
        bb2[i] = ob2[i];
        #pragma unroll
        for (int j = 0; j < 8; ++j) w2v[i][j] = ow2[i * 8 + j];
    }

    float* op = zscr + (size_t)b * Tn * zstride;
    for (int t = 0; t < Tn; ++t) {
        float a[8];
        #pragma unroll
        for (int j = 0; j < 8; ++j) {
            float u = fmaf(w1[j][0], z0, bb1[j]);
            u = fmaf(w1[j][1], z1, u);
            u = fmaf(w1[j][2], z2, u);
            a[j] = fast_tanh(u);
        }
        float d0 = bb2[0], d1 = bb2[1], d2 = bb2[2];
        #pragma unroll
        for (int j = 0; j < 8; ++j) {
            d0 = fmaf(w2v[0][j], a[j], d0);
            d1 = fmaf(w2v[1][j], a[j], d1);
            d2 = fmaf(w2v[2][j], a[j], d2);
        }
        z0 = fmaf(0.1f, d0, z0);
        z1 = fmaf(0.1f, d1, z1);
        z2 = fmaf(0.1f, d2, z2);
        op[t * zstride + 0] = z0; op[t * zstride + 1] = z1; op[t * zstride + 2] = z2;
    }
}

// K3: decode x_pred rows. Same structure as K1's decode: R=4 rows/thread
// (weight s_load amortization), 72 KB LDS tile, dense float4 store of the
// block's contiguous 1024 rows. z reads are dense ([b][t] scratch order).
__global__ __launch_bounds__(256) void k3_decpred(
    const float* __restrict__ dw1, const float* __restrict__ db1,
    const float* __restrict__ dg,  const float* __restrict__ dbn,
    const float* __restrict__ dm,  const float* __restrict__ dv,
    const float* __restrict__ dw2, const float* __restrict__ db2,
    const float* __restrict__ zscr, int zstride,
    float* __restrict__ xpred)
{
    const int s = threadIdx.x;
    constexpr int ROWS    = R * 256;          // 1024 rows per block
    constexpr int TILE_F  = ROWS * Dn;        // 18432 floats = 73728 B
    constexpr int TILE_F4 = TILE_F / 4;

    __shared__ float ot[TILE_F];

    const size_t row0 = (size_t)blockIdx.x * ROWS + s;   // row r = row0 + r*256

    // z reads (dense: zidx = row * zstride), all before any global store
    float zz[R][Ln];
    #pragma unroll
    for (int r = 0; r < R; ++r) {
        size_t zidx = (row0 + (size_t)r * 256) * zstride;
        zz[r][0] = zscr[zidx + 0];
        zz[r][1] = zscr[zidx + 1];
        zz[r][2] = zscr[zidx + 2];
    }

    float h2[R][Hn];
    #pragma unroll
    for (int j = 0; j < Hn; ++j) {
        float w0 = dw1[j * Ln + 0], w1 = dw1[j * Ln + 1], w2 = dw1[j * Ln + 2];
        float b  = db1[j];
        float sc = dg[j] / sqrtf(dv[j] + EPS);
        float sh = dbn[j] - dm[j] * sc;
        #pragma unroll
        for (int r = 0; r < R; ++r) {
            float a = fmaf(w0, zz[r][0], b);
            a = fmaf(w1, zz[r][1], a);
            a = fmaf(w2, zz[r][2], a);
            h2[r][j] = fmaf(fmaxf(a, 0.0f), sc, sh);
        }
    }
    #pragma unroll
    for (int m = 0; m < Dn; m += 2) {
        float o0[R], o1[R];
        #pragma unroll
        for (int r = 0; r < R; ++r) { o0[r] = db2[m]; o1[r] = db2[m + 1]; }
        #pragma unroll
        for (int j = 0; j < Hn; ++j) {
            float wa = dw2[m * Hn + j];
            float wb = dw2[(m + 1) * Hn + j];
            #pragma unroll
            for (int r = 0; r < R; ++r) {
                o0[r] = fmaf(wa, h2[r][j], o0[r]);
                o1[r] = fmaf(wb, h2[r][j], o1[r]);
            }
        }
        #pragma unroll
        for (int r = 0; r < R; ++r) {
            ot[(r * 256 + s) * Dn + m]     = o0[r];
            ot[(r * 256 + s) * Dn + m + 1] = o1[r];
        }
    }
    __syncthreads();

    float4* og = reinterpret_cast<float4*>(xpred + (size_t)blockIdx.x * TILE_F);
    const float4* ot4 = reinterpret_cast<const float4*>(ot);
    #pragma unroll 4
    for (int i = s; i < TILE_F4; i += 256) og[i] = ot4[i];
}

extern "C" void kernel_launch(void* const* d_in, const int* in_sizes, int n_in,
                              void* d_out, int out_size, void* d_ws, size_t ws_size,
                              hipStream_t stream)
{
    const float* x   = (const float*)d_in[0];
    // d_in[1] = t_span: only its length (T=64) matters; unused at runtime.
    const float* ew1 = (const float*)d_in[2];
    const float* eb1 = (const float*)d_in[3];
    const float* eg  = (const float*)d_in[4];
    const float* ebb = (const float*)d_in[5];
    const float* em  = (const float*)d_in[6];
    const float* ev  = (const float*)d_in[7];
    const float* ew2 = (const float*)d_in[8];
    const float* eb2 = (const float*)d_in[9];
    const float* dw1 = (const float*)d_in[10];
    const float* db1 = (const float*)d_in[11];
    const float* dg  = (const float*)d_in[12];
    const float* dbn = (const float*)d_in[13];
    const float* dm  = (const float*)d_in[14];
    const float* dv  = (const float*)d_in[15];
    const float* dw2 = (const float*)d_in[16];
    const float* db2 = (const float*)d_in[17];
    const float* ow1 = (const float*)d_in[18];
    const float* ob1 = (const float*)d_in[19];
    const float* ow2 = (const float*)d_in[20];
    const float* ob2 = (const float*)d_in[21];
    const float* cw1 = (const float*)d_in[22];
    const float* cb1 = (const float*)d_in[23];
    const float* cw2 = (const float*)d_in[24];
    const float* cb2 = (const float*)d_in[25];

    float* out   = (float*)d_out;
    float* xrec  = out;
    float* xpred = out + OFF_XP;
    float* prob  = out + OFF_PROB;
    float* zseq  = out + OFF_ZS;

    // z-trajectory scratch: prefer d_ws ([b][t][3]); fallback stashes z in
    // the first 12 B of each x_pred row ([b][t] stride 18).
    const size_t zbytes = (size_t)Bn * Tn * Ln * sizeof(float);
    float* zscr; int zstride;
    if (ws_size >= zbytes) { zscr = (float*)d_ws; zstride = Ln; }
    else                   { zscr = xpred;        zstride = Dn; }

    k1_encdec<<<dim3(Bn / R), dim3(Sn), 0, stream>>>(
        x, ew1, eb1, eg, ebb, em, ev, ew2, eb2,
        dw1, db1, dg, dbn, dm, dv, dw2, db2,
        cw1, cb1, cw2, cb2, xrec, prob, zseq);

    k2_ode<<<dim3(Bn / 64), dim3(64), 0, stream>>>(
        zseq, ow1, ob1, ow2, ob2, zscr, zstride);

    k3_decpred<<<dim3((Bn * Tn) / (R * 256)), dim3(256), 0, stream>>>(
        dw1, db1, dg, dbn, dm, dv, dw2, db2, zscr, zstride, xpred);
}

// Round 14
// 262.934 us; speedup vs baseline: 1.1154x; 1.0384x over previous
//
#include <hip/hip_runtime.h>
#include <math.h>

// Problem constants (fixed by reference setup_inputs)
constexpr int Bn = 4096, Sn = 256, Tn = 64;
constexpr int Dn = 18, Hn = 16, Ln = 3;
constexpr float EPS = 1e-5f;

// d_out layout: x_recon (B,S,D) | x_pred (B,T,D) | prob (B,1) | z_seq (B,S,L)
constexpr size_t OFF_XP   = (size_t)Bn * Sn * Dn;            // 18874368
constexpr size_t OFF_PROB = OFF_XP + (size_t)Bn * Tn * Dn;   // 23592960
constexpr size_t OFF_ZS   = OFF_PROB + (size_t)Bn;           // 23597056

// flat accessor into out_[4][18] with a static element index (all uses unrolled)
#define OF(e) out_[(e) / Dn][(e) % Dn]

__device__ __forceinline__ float fast_tanh(float x) {
    float ax = fabsf(x);
    float e  = __expf(-2.0f * ax);
    float r  = (1.0f - e) / (1.0f + e);
    return copysignf(r, x);
}

// K1: fused encode -> z_seq -> decode -> x_recon + per-wave z_mean/classifier.
// R12 structure (post R11 counters: traffic ideal at 126 MB but 86% wave-stall;
// VALUBusy pinned ~30% across all variants):
//  - Thread s owns 4 CONSECUTIVE rows (block = 1024 contiguous rows = 4 batches;
//    wave w = batch 4*blockIdx+w). Per-thread 72-float contiguous spans ->
//    dense float4 x loads / x_recon stores / z_seq stores. NO LDS, NO barriers.
//  - Fused j-loops (unroll 2): h_j consumed immediately (no h array, no dynamic
//    indexing). Code ~6x smaller than the R11 full unroll (I-cache theory) and
//    VGPR ~115 (xv[72] / out_[72] in disjoint phases) -> <=128 -> all 16
//    waves/CU resident (occ ~50%, TLP theory).
//  - Weights stream through SGPRs once per 4 rows (amortization kept).
__global__ __launch_bounds__(256) void k1_encdec(
    const float* __restrict__ x,
    const float* __restrict__ ew1, const float* __restrict__ eb1,
    const float* __restrict__ eg,  const float* __restrict__ ebb,
    const float* __restrict__ em,  const float* __restrict__ ev,
    const float* __restrict__ ew2, const float* __restrict__ eb2,
    const float* __restrict__ dw1, const float* __restrict__ db1,
    const float* __restrict__ dg,  const float* __restrict__ dbn,
    const float* __restrict__ dm,  const float* __restrict__ dv,
    const float* __restrict__ dw2, const float* __restrict__ db2,
    const float* __restrict__ cw1, const float* __restrict__ cb1,
    const float* __restrict__ cw2, const float* __restrict__ cb2,
    float* __restrict__ xrec, float* __restrict__ prob, float* __restrict__ zseq)
{
    const int s = threadIdx.x;
    const size_t rowBase = (size_t)blockIdx.x * 1024 + 4 * (size_t)s;

    // ---- dense x load: 72 consecutive floats = 18 float4 ----
    float xv[72];
    {
        const float4* xg = reinterpret_cast<const float4*>(x + rowBase * Dn);
        #pragma unroll
        for (int i = 0; i < 18; ++i) {
            float4 t = xg[i];
            xv[4*i+0] = t.x; xv[4*i+1] = t.y; xv[4*i+2] = t.z; xv[4*i+3] = t.w;
        }
    }

    // ---- fused encode: z accumulators, h_j consumed on the fly ----
    float zz[4][Ln];
    #pragma unroll
    for (int c = 0; c < Ln; ++c) {
        float b = eb2[c];
        #pragma unroll
        for (int r = 0; r < 4; ++r) zz[r][c] = b;
    }
    #pragma unroll 2
    for (int j = 0; j < Hn; ++j) {
        const float* wr = ew1 + j * Dn;       // contiguous row, uniform -> s_loads
        float w[Dn];
        #pragma unroll
        for (int k = 0; k < Dn; ++k) w[k] = wr[k];
        float bj  = eb1[j];
        float scj = eg[j] / sqrtf(ev[j] + EPS);
        float shj = ebb[j] - em[j] * scj;
        float e0 = ew2[0 * Hn + j], e1 = ew2[1 * Hn + j], e2 = ew2[2 * Hn + j];
        #pragma unroll
        for (int r = 0; r < 4; ++r) {
            float a = bj;
            #pragma unroll
            for (int k = 0; k < Dn; ++k) a = fmaf(w[k], xv[r * Dn + k], a);
            a = fmaf(fmaxf(a, 0.0f), scj, shj);   // relu + folded BN
            zz[r][0] = fmaf(e0, a, zz[r][0]);
            zz[r][1] = fmaf(e1, a, zz[r][1]);
            zz[r][2] = fmaf(e2, a, zz[r][2]);
        }
    }

    // ---- z_seq store: 12 consecutive floats = 3 float4 ----
    {
        float4* zp4 = reinterpret_cast<float4*>(zseq + rowBase * Ln);
        zp4[0] = make_float4(zz[0][0], zz[0][1], zz[0][2], zz[1][0]);
        zp4[1] = make_float4(zz[1][1], zz[1][2], zz[2][0], zz[2][1]);
        zp4[2] = make_float4(zz[2][2], zz[3][0], zz[3][1], zz[3][2]);
    }

    // ---- fused decode: out_[4][18] accumulates over j; h2_j on the fly ----
    float out_[4][Dn];
    #pragma unroll
    for (int m = 0; m < Dn; ++m) {
        float b = db2[m];
        #pragma unroll
        for (int r = 0; r < 4; ++r) out_[r][m] = b;
    }
    #pragma unroll 2
    for (int j = 0; j < Hn; ++j) {
        float w0 = dw1[j * Ln + 0], w1 = dw1[j * Ln + 1], w2 = dw1[j * Ln + 2];
        float bj  = db1[j];
        float scj = dg[j] / sqrtf(dv[j] + EPS);
        float shj = dbn[j] - dm[j] * scj;
        float wc[Dn];
        #pragma unroll
        for (int m = 0; m < Dn; ++m) wc[m] = dw2[m * Hn + j];  // column j (uniform scalars)
        #pragma unroll
        for (int r = 0; r < 4; ++r) {
            float a = fmaf(w0, zz[r][0], bj);
            a = fmaf(w1, zz[r][1], a);
            a = fmaf(w2, zz[r][2], a);
            a = fmaf(fmaxf(a, 0.0f), scj, shj);
            #pragma unroll
            for (int m = 0; m < Dn; ++m) out_[r][m] = fmaf(wc[m], a, out_[r][m]);
        }
    }

    // ---- dense x_recon store: 72 consecutive floats = 18 float4 ----
    {
        float4* og = reinterpret_cast<float4*>(xrec + rowBase * Dn);
        #pragma unroll
        for (int i = 0; i < 18; ++i) {
            int e = 4 * i;
            og[i] = make_float4(OF(e), OF(e + 1), OF(e + 2), OF(e + 3));
        }
    }

    // ---- per-wave z_mean + classifier (wave = one batch; no LDS/barrier) ----
    float a0 = zz[0][0] + zz[1][0] + zz[2][0] + zz[3][0];
    float a1 = zz[0][1] + zz[1][1] + zz[2][1] + zz[3][1];
    float a2 = zz[0][2] + zz[1][2] + zz[2][2] + zz[3][2];
    #pragma unroll
    for (int off = 32; off > 0; off >>= 1) {
        a0 += __shfl_down(a0, off);
        a1 += __shfl_down(a1, off);
        a2 += __shfl_down(a2, off);
    }
    const int lane = s & 63, wid = s >> 6;
    if (lane == 0) {
        float m0 = a0 * (1.0f / Sn), m1 = a1 * (1.0f / Sn), m2 = a2 * (1.0f / Sn);
        float logit = cb2[0];
        #pragma unroll
        for (int j = 0; j < 4; ++j) {
            float a = fmaf(cw1[j * 3 + 0], m0, cb1[j]);
            a = fmaf(cw1[j * 3 + 1], m1, a);
            a = fmaf(cw1[j * 3 + 2], m2, a);
            a = fmaxf(a, 0.0f);
            logit = fmaf(cw2[j], a, logit);
        }
        prob[blockIdx.x * 4 + wid] = 1.0f / (1.0f + __expf(-logit));
    }
}

// K2: sequential ODE scan, one thread per batch element; 64 blocks x 64
// threads (latency-bound serial chain spread across CUs).
// Scratch layout [b][t]*zstride (zstride=3 in d_ws; fallback zstride=18 into
// x_pred rows). [b][t] order makes K3's reads dense; K2's scattered stores
// are 3 MB absorbed by L2/L3.
__global__ __launch_bounds__(64) void k2_ode(
    const float* __restrict__ zseq,
    const float* __restrict__ ow1, const float* __restrict__ ob1,
    const float* __restrict__ ow2, const float* __restrict__ ob2,
    float* __restrict__ zscr, int zstride)
{
    const int b = blockIdx.x * blockDim.x + threadIdx.x;
    const float* zp = zseq + ((size_t)b * Sn + (Sn - 1)) * Ln;
    float z0 = zp[0], z1 = zp[1], z2 = zp[2];

    float w1[8][3], bb1[8], w2v[3][8], bb2[3];
    #pragma unroll
    for (int j = 0; j < 8; ++j) {
        bb1[j] = ob1[j];
        #pragma unroll
        for (int k = 0; k < 3; ++k) w1[j][k] = ow1[j * 3 + k];
    }
    #pragma unroll
    for (int i = 0; i < 3; ++i) {
        bb2[i] = ob2[i];
        #pragma unroll
        for (int j = 0; j < 8; ++j) w2v[i][j] = ow2[i * 8 + j];
    }

    float* op = zscr + (size_t)b * Tn * zstride;
    for (int t = 0; t < Tn; ++t) {
        float a[8];
        #pragma unroll
        for (int j = 0; j < 8; ++j) {
            float u = fmaf(w1[j][0], z0, bb1[j]);
            u = fmaf(w1[j][1], z1, u);
            u = fmaf(w1[j][2], z2, u);
            a[j] = fast_tanh(u);
        }
        float d0 = bb2[0], d1 = bb2[1], d2 = bb2[2];
        #pragma unroll
        for (int j = 0; j < 8; ++j) {
            d0 = fmaf(w2v[0][j], a[j], d0);
            d1 = fmaf(w2v[1][j], a[j], d1);
            d2 = fmaf(w2v[2][j], a[j], d2);
        }
        z0 = fmaf(0.1f, d0, z0);
        z1 = fmaf(0.1f, d1, z1);
        z2 = fmaf(0.1f, d2, z2);
        op[t * zstride + 0] = z0;
        op[t * zstride + 1] = z1;
        op[t * zstride + 2] = z2;
    }
}

// K3: decode x_pred rows. Same R12 structure as K1's decode: 4 consecutive
// rows per thread, fused j-loop, dense float4 loads/stores, no LDS/barriers.
__global__ __launch_bounds__(256) void k3_decpred(
    const float* __restrict__ dw1, const float* __restrict__ db1,
    const float* __restrict__ dg,  const float* __restrict__ dbn,
    const float* __restrict__ dm,  const float* __restrict__ dv,
    const float* __restrict__ dw2, const float* __restrict__ db2,
    const float* __restrict__ zscr, int zstride,
    float* __restrict__ xpred)
{
    const int s = threadIdx.x;
    const size_t rowBase = (size_t)blockIdx.x * 1024 + 4 * (size_t)s;

    float zz[4][Ln];
    if (zstride == Ln) {
        // dense: 12 consecutive floats = 3 float4
        const float4* zp4 = reinterpret_cast<const float4*>(zscr + rowBase * Ln);
        float4 t0 = zp4[0], t1 = zp4[1], t2 = zp4[2];
        zz[0][0] = t0.x; zz[0][1] = t0.y; zz[0][2] = t0.z; zz[1][0] = t0.w;
        zz[1][1] = t1.x; zz[1][2] = t1.y; zz[2][0] = t1.z; zz[2][1] = t1.w;
        zz[2][2] = t2.x; zz[3][0] = t2.y; zz[3][1] = t2.z; zz[3][2] = t2.w;
    } else {
        #pragma unroll
        for (int r = 0; r < 4; ++r) {
            size_t zidx = (rowBase + r) * (size_t)zstride;
            zz[r][0] = zscr[zidx + 0];
            zz[r][1] = zscr[zidx + 1];
            zz[r][2] = zscr[zidx + 2];
        }
    }

    float out_[4][Dn];
    #pragma unroll
    for (int m = 0; m < Dn; ++m) {
        float b = db2[m];
        #pragma unroll
        for (int r = 0; r < 4; ++r) out_[r][m] = b;
    }
    #pragma unroll 2
    for (int j = 0; j < Hn; ++j) {
        float w0 = dw1[j * Ln + 0], w1 = dw1[j * Ln + 1], w2 = dw1[j * Ln + 2];
        float bj  = db1[j];
        float scj = dg[j] / sqrtf(dv[j] + EPS);
        float shj = dbn[j] - dm[j] * scj;
        float wc[Dn];
        #pragma unroll
        for (int m = 0; m < Dn; ++m) wc[m] = dw2[m * Hn + j];
        #pragma unroll
        for (int r = 0; r < 4; ++r) {
            float a = fmaf(w0, zz[r][0], bj);
            a = fmaf(w1, zz[r][1], a);
            a = fmaf(w2, zz[r][2], a);
            a = fmaf(fmaxf(a, 0.0f), scj, shj);
            #pragma unroll
            for (int m = 0; m < Dn; ++m) out_[r][m] = fmaf(wc[m], a, out_[r][m]);
        }
    }

    float4* og = reinterpret_cast<float4*>(xpred + rowBase * Dn);
    #pragma unroll
    for (int i = 0; i < 18; ++i) {
        int e = 4 * i;
        og[i] = make_float4(OF(e), OF(e + 1), OF(e + 2), OF(e + 3));
    }
}

extern "C" void kernel_launch(void* const* d_in, const int* in_sizes, int n_in,
                              void* d_out, int out_size, void* d_ws, size_t ws_size,
                              hipStream_t stream)
{
    const float* x   = (const float*)d_in[0];
    // d_in[1] = t_span: only its length (T=64) matters; unused at runtime.
    const float* ew1 = (const float*)d_in[2];
    const float* eb1 = (const float*)d_in[3];
    const float* eg  = (const float*)d_in[4];
    const float* ebb = (const float*)d_in[5];
    const float* em  = (const float*)d_in[6];
    const float* ev  = (const float*)d_in[7];
    const float* ew2 = (const float*)d_in[8];
    const float* eb2 = (const float*)d_in[9];
    const float* dw1 = (const float*)d_in[10];
    const float* db1 = (const float*)d_in[11];
    const float* dg  = (const float*)d_in[12];
    const float* dbn = (const float*)d_in[13];
    const float* dm  = (const float*)d_in[14];
    const float* dv  = (const float*)d_in[15];
    const float* dw2 = (const float*)d_in[16];
    const float* db2 = (const float*)d_in[17];
    const float* ow1 = (const float*)d_in[18];
    const float* ob1 = (const float*)d_in[19];
    const float* ow2 = (const float*)d_in[20];
    const float* ob2 = (const float*)d_in[21];
    const float* cw1 = (const float*)d_in[22];
    const float* cb1 = (const float*)d_in[23];
    const float* cw2 = (const float*)d_in[24];
    const float* cb2 = (const float*)d_in[25];

    float* out   = (float*)d_out;
    float* xrec  = out;
    float* xpred = out + OFF_XP;
    float* prob  = out + OFF_PROB;
    float* zseq  = out + OFF_ZS;

    // z-trajectory scratch: prefer d_ws ([b][t][3]); fallback stashes z in
    // the first 12 B of each x_pred row ([b][t] stride 18).
    const size_t zbytes = (size_t)Bn * Tn * Ln * sizeof(float);
    float* zscr; int zstride;
    if (ws_size >= zbytes) { zscr = (float*)d_ws; zstride = Ln; }
    else                   { zscr = xpred;        zstride = Dn; }

    k1_encdec<<<dim3(Bn * Sn / 1024), dim3(256), 0, stream>>>(
        x, ew1, eb1, eg, ebb, em, ev, ew2, eb2,
        dw1, db1, dg, dbn, dm, dv, dw2, db2,
        cw1, cb1, cw2, cb2, xrec, prob, zseq);

    k2_ode<<<dim3(Bn / 64), dim3(64), 0, stream>>>(
        zseq, ow1, ob1, ow2, ob2, zscr, zstride);

    k3_decpred<<<dim3(Bn * Tn / 1024), dim3(256), 0, stream>>>(
        dw1, db1, dg, dbn, dm, dv, dw2, db2, zscr, zstride, xpred);
}